// Round 2
// baseline (1518.718 us; speedup 1.0000x reference)
//
#include <hip/hip_runtime.h>
#include <hip/hip_bf16.h>
#include <math.h>

#define LOG2E_F 1.4426950408889634f

static constexpr int BT = 64;
static constexpr int DK = 64;
static constexpr int DV = 64;
static constexpr float SCALE = 0.125f;

__device__ __forceinline__ float logsig_log2e(float x){
    float l = (x >= 0.f) ? (-log1pf(expf(-x))) : (x - log1pf(expf(x)));
    return l * LOG2E_F;
}

// ===================== Stage A: per-chunk local state =====================
// A_t = kdec_loc^T @ v (64x64), nloc_t = sum kdec_loc, plus fl_t, mloc_t.
// Grid (NT, BH). A stored V-slab-major: [(s*NT+t)*4 + vslab][row][16].
__global__ __launch_bounds__(256) void stageA_kernel(
    const float* __restrict__ kg, const float* __restrict__ vg,
    const float* __restrict__ ig, const float* __restrict__ fg,
    float* __restrict__ A_ws, float* __restrict__ nloc_ws,
    float* __restrict__ fl_ws, float* __restrict__ mloc_ws,
    int T, int NT)
{
    const int ct = blockIdx.x, s = blockIdx.y, tid = threadIdx.x;

    __shared__ __align__(16) float kbuf[BT][DK];   // pre-scaled by gsc[row]
    __shared__ __align__(16) float vbuf[BT][DV];
    __shared__ float gsc[BT];

    const size_t rowbase = (size_t)s * T + (size_t)ct * BT;
    const float* kc = kg + rowbase * DK;
    const float* vc = vg + rowbase * DV;

    // global loads into registers (in flight during gate compute)
    float4 kr[4], vr[4];
    #pragma unroll
    for (int i = 0; i < 4; ++i){
        int idx = i * 1024 + tid * 4;
        kr[i] = *(const float4*)(kc + idx);
        vr[i] = *(const float4*)(vc + idx);
    }
    // gates (wave 0)
    if (tid < 64){
        float b = logsig_log2e(fg[rowbase + tid]);
        #pragma unroll
        for (int off = 1; off < 64; off <<= 1){
            float y = __shfl_up(b, off);
            if (tid >= off) b += y;
        }
        float f_last = __shfl(b, 63);
        float a = ig[rowbase + tid] * LOG2E_F - b;
        float p = a;
        #pragma unroll
        for (int off = 32; off > 0; off >>= 1) p = fmaxf(p, __shfl_xor(p, off));
        gsc[tid] = exp2f(a - p);          // exp2(g - mloc), mloc = f_last + amax
        if (tid == 0){ fl_ws[s * NT + ct] = f_last; mloc_ws[s * NT + ct] = f_last + p; }
    }
    __syncthreads();
    // scale k rows by gsc, stage both into LDS
    #pragma unroll
    for (int i = 0; i < 4; ++i){
        int idx = i * 1024 + tid * 4;
        int r = idx >> 6, c = idx & 63;
        float g = gsc[r];
        kbuf[r][c]   = kr[i].x * g; kbuf[r][c+1] = kr[i].y * g;
        kbuf[r][c+2] = kr[i].z * g; kbuf[r][c+3] = kr[i].w * g;
        vbuf[r][c]   = vr[i].x; vbuf[r][c+1] = vr[i].y;
        vbuf[r][c+2] = vr[i].z; vbuf[r][c+3] = vr[i].w;
    }
    __syncthreads();

    const int r0 = (tid >> 4) * 4;      // A row (k-dim)
    const int c0 = (tid & 15) * 4;      // A col (v-dim)
    float acc[4][4] = {};
    for (int c = 0; c < BT; ++c){
        float4 kd = *(const float4*)&kbuf[c][r0];
        float4 vv = *(const float4*)&vbuf[c][c0];
        float k4[4] = {kd.x, kd.y, kd.z, kd.w};
        float v4[4] = {vv.x, vv.y, vv.z, vv.w};
        #pragma unroll
        for (int j = 0; j < 4; ++j)
            #pragma unroll
            for (int jj = 0; jj < 4; ++jj)
                acc[j][jj] = fmaf(k4[j], v4[jj], acc[j][jj]);
    }
    const int vbs = c0 >> 4, ci = c0 & 15;
    float* Ab = A_ws + (((size_t)(s * NT + ct)) * 4 + vbs) * 1024 + ci;
    #pragma unroll
    for (int j = 0; j < 4; ++j)
        *(float4*)(Ab + (size_t)(r0 + j) * 16) = make_float4(acc[j][0], acc[j][1], acc[j][2], acc[j][3]);

    if (tid < 64){
        float a = 0.f;
        for (int c = 0; c < BT; ++c) a += kbuf[c][tid];
        nloc_ws[((size_t)(s * NT + ct)) * DK + tid] = a;
    }
}

// ===================== Stage B: sequential combine =====================
// Grid (4, BH): block owns one 16-col V-slab of C for one sequence.
// m-recurrence precomputed via max-plus shfl scan -> dependency-free loop.
__global__ __launch_bounds__(256) void stageB_kernel(
    const float* __restrict__ A_ws, const float* __restrict__ nloc_ws,
    const float* __restrict__ fl_ws, const float* __restrict__ mloc_ws,
    float* __restrict__ Cws, float* __restrict__ nws, float* __restrict__ mws,
    int NT)
{
    const int vb = blockIdx.x, s = blockIdx.y, tid = threadIdx.x;
    __shared__ float decs[64], scs[64];

    if (tid < 64){
        float fl = fl_ws[s * NT + tid];
        float ml = mloc_ws[s * NT + tid];
        // inclusive max-plus scan of maps x -> max(x+fl, ml)
        float F = fl, G = ml;
        #pragma unroll
        for (int off = 1; off < 64; off <<= 1){
            float Fp = __shfl_up(F, off);
            float Gp = __shfl_up(G, off);
            if (tid >= off){ G = fmaxf(Gp + F, G); F = Fp + F; }
        }
        float m_next = fmaxf(F, G);               // m_{t+1} at lane t
        float m_cur  = __shfl_up(m_next, 1);
        if (tid == 0) m_cur = 0.f;                // m_0 = 0
        decs[tid] = exp2f(fl + m_cur - m_next);
        scs[tid]  = exp2f(ml - m_next);
        if (vb == 0) mws[s * NT + tid] = m_cur;
    }
    __syncthreads();

    const size_t base = (size_t)s * NT * 4096 + (size_t)vb * 1024 + tid * 4;
    const float* Ab = A_ws + base;
    float*       Cb = Cws  + base;
    const bool do_n = (vb == 0) && (tid < 64);

    float4 C4 = make_float4(0.f, 0.f, 0.f, 0.f);
    float nreg = 0.f;
    float4 p[8]; float nl[8];
    #pragma unroll
    for (int i = 0; i < 8; ++i){
        p[i] = *(const float4*)(Ab + (size_t)i * 4096);
        nl[i] = 0.f;
    }
    if (do_n){
        #pragma unroll
        for (int i = 0; i < 8; ++i) nl[i] = nloc_ws[((size_t)(s * NT + i)) * DK + tid];
    }
    const float4 z4 = make_float4(0.f, 0.f, 0.f, 0.f);

    for (int t0 = 0; t0 < NT; t0 += 8){
        float4 q[8]; float nq[8];
        const int tn = t0 + 8;
        #pragma unroll
        for (int i = 0; i < 8; ++i)
            q[i] = (tn + i < NT) ? *(const float4*)(Ab + (size_t)(tn + i) * 4096) : z4;
        #pragma unroll
        for (int i = 0; i < 8; ++i) nq[i] = 0.f;
        if (do_n){
            #pragma unroll
            for (int i = 0; i < 8; ++i)
                if (tn + i < NT) nq[i] = nloc_ws[((size_t)(s * NT + tn + i)) * DK + tid];
        }
        #pragma unroll
        for (int i = 0; i < 8; ++i){
            const int t = t0 + i;
            *(float4*)(Cb + (size_t)t * 4096) = C4;          // state ENTERING chunk t
            if (do_n) nws[((size_t)(s * NT + t)) * DK + tid] = nreg;
            const float d = decs[t], sc = scs[t];
            C4.x = C4.x * d + p[i].x * sc;
            C4.y = C4.y * d + p[i].y * sc;
            C4.z = C4.z * d + p[i].z * sc;
            C4.w = C4.w * d + p[i].w * sc;
            if (do_n) nreg = nreg * d + nl[i] * sc;
        }
        #pragma unroll
        for (int i = 0; i < 8; ++i){ p[i] = q[i]; nl[i] = nq[i]; }
    }
}

// ===================== Pass 2: per-chunk outputs (b128 LDS) =====================
__global__ __launch_bounds__(256) void pass2_kernel(
    const float* __restrict__ qg, const float* __restrict__ kg, const float* __restrict__ vg,
    const float* __restrict__ ig, const float* __restrict__ fg,
    const float* __restrict__ Cws, const float* __restrict__ nws, const float* __restrict__ mws,
    float* __restrict__ out, int T, int NT)
{
    const int ct  = blockIdx.x;
    const int s   = blockIdx.y;
    const int tid = threadIdx.x;
    const int lane = tid & 63;

    __shared__ __align__(16) float X[BT][68];   // q -> v
    __shared__ __align__(16) float Y[BT][68];   // k -> C
    __shared__ __align__(16) float Z[BT][68];   // S
    __shared__ float colterm[BT], Mr[BT], rowfac[BT], dncl[BT];
    __shared__ __align__(16) float nsh[DK];
    __shared__ float qn[BT], rowsum[BT], denom[BT];

    const size_t rowbase = (size_t)s * T + (size_t)ct * BT;
    const float* qc = qg + rowbase * DK;
    const float* kc = kg + rowbase * DK;
    const float* vc = vg + rowbase * DV;
    const float* Cc = Cws + ((size_t)(s * NT + ct)) * 4096;   // slab-major
    const float* nc = nws + ((size_t)(s * NT + ct)) * DK;
    const float m   = mws[s * NT + ct];

    if (tid < 64){
        float b = logsig_log2e(fg[rowbase + lane]);
        #pragma unroll
        for (int off = 1; off < 64; off <<= 1){
            float y = __shfl_up(b, off);
            if (lane >= off) b += y;
        }
        float a = ig[rowbase + lane] * LOG2E_F - b;
        float p = a;
        #pragma unroll
        for (int off = 1; off < 64; off <<= 1){
            float y = __shfl_up(p, off);
            if (lane >= off) p = fmaxf(p, y);
        }
        float M = fmaxf(m, p);
        colterm[lane] = a;
        Mr[lane] = M;
        rowfac[lane] = SCALE * exp2f(m - M);
        dncl[lane] = exp2f(-(b + M));
        nsh[lane] = nc[lane];
    }
    #pragma unroll
    for (int i = 0; i < 4; ++i){
        int idx = i * 1024 + tid * 4;
        int r = idx >> 6, c = idx & 63;
        *(float4*)&X[r][c] = *(const float4*)(qc + idx);
        *(float4*)&Y[r][c] = *(const float4*)(kc + idx);
    }
    __syncthreads();

    const int r0 = (tid >> 4) * 4;
    const int c0 = (tid & 15) * 4;
    const int v0 = c0;

    // ---- S = q k^T (raw); scale + mask + store Z + rowsum ----
    float sacc[4][4] = {};
    for (int x = 0; x < DK; x += 4){
        float xr[4][4], yc[4][4];
        #pragma unroll
        for (int j = 0; j < 4; ++j){
            float4 t4 = *(const float4*)&X[r0 + j][x];
            xr[j][0] = t4.x; xr[j][1] = t4.y; xr[j][2] = t4.z; xr[j][3] = t4.w;
        }
        #pragma unroll
        for (int j = 0; j < 4; ++j){
            float4 t4 = *(const float4*)&Y[c0 + j][x];
            yc[j][0] = t4.x; yc[j][1] = t4.y; yc[j][2] = t4.z; yc[j][3] = t4.w;
        }
        #pragma unroll
        for (int j = 0; j < 4; ++j)
            #pragma unroll
            for (int jj = 0; jj < 4; ++jj)
                #pragma unroll
                for (int xx = 0; xx < 4; ++xx)
                    sacc[j][jj] = fmaf(xr[j][xx], yc[jj][xx], sacc[j][jj]);
    }
    float rs[4];
    #pragma unroll
    for (int j = 0; j < 4; ++j){
        int r = r0 + j;
        float Mrv = Mr[r];
        float z[4];
        #pragma unroll
        for (int jj = 0; jj < 4; ++jj){
            int c = c0 + jj;
            z[jj] = (c <= r) ? sacc[j][jj] * SCALE * exp2f(colterm[c] - Mrv) : 0.f;
        }
        *(float4*)&Z[r][c0] = make_float4(z[0], z[1], z[2], z[3]);
        rs[j] = z[0] + z[1] + z[2] + z[3];
    }
    #pragma unroll
    for (int off = 1; off < 16; off <<= 1){
        #pragma unroll
        for (int j = 0; j < 4; ++j) rs[j] += __shfl_xor(rs[j], off);
    }
    if ((tid & 15) == 0){
        #pragma unroll
        for (int j = 0; j < 4; ++j) rowsum[r0 + j] = rs[j];
    }
    __syncthreads();

    // ---- load C (slab-major) into Y; qn = q . n ----
    #pragma unroll
    for (int i = 0; i < 4; ++i){
        int idx = i * 1024 + tid * 4;
        int vbs = idx >> 10, r = (idx >> 4) & 63, cin = idx & 15;
        *(float4*)&Y[r][vbs * 16 + cin] = *(const float4*)(Cc + idx);
    }
    if (tid < 64){
        float acc = 0.f;
        for (int x = 0; x < DK; x += 4){
            float4 xq = *(const float4*)&X[lane][x];
            float4 nn = *(const float4*)&nsh[x];
            acc = fmaf(xq.x, nn.x, acc); acc = fmaf(xq.y, nn.y, acc);
            acc = fmaf(xq.z, nn.z, acc); acc = fmaf(xq.w, nn.w, acc);
        }
        qn[lane] = acc;
    }
    __syncthreads();

    // ---- acc1 = q @ C ----
    float acc1[4][4] = {};
    for (int x = 0; x < DK; x += 4){
        float xr[4][4], yv[4][4];
        #pragma unroll
        for (int j = 0; j < 4; ++j){
            float4 t4 = *(const float4*)&X[r0 + j][x];
            xr[j][0] = t4.x; xr[j][1] = t4.y; xr[j][2] = t4.z; xr[j][3] = t4.w;
        }
        #pragma unroll
        for (int xx = 0; xx < 4; ++xx){
            float4 t4 = *(const float4*)&Y[x + xx][v0];
            yv[xx][0] = t4.x; yv[xx][1] = t4.y; yv[xx][2] = t4.z; yv[xx][3] = t4.w;
        }
        #pragma unroll
        for (int j = 0; j < 4; ++j)
            #pragma unroll
            for (int jj = 0; jj < 4; ++jj)
                #pragma unroll
                for (int xx = 0; xx < 4; ++xx)
                    acc1[j][jj] = fmaf(xr[j][xx], yv[xx][jj], acc1[j][jj]);
    }
    __syncthreads();

    // ---- load v into X; denom ----
    #pragma unroll
    for (int i = 0; i < 4; ++i){
        int idx = i * 1024 + tid * 4;
        int r = idx >> 6, c = idx & 63;
        *(float4*)&X[r][c] = *(const float4*)(vc + idx);
    }
    if (tid < 64){
        float dn = fabsf(rowfac[lane] * qn[lane] + rowsum[lane]);
        denom[lane] = fmaxf(dn, dncl[lane]);
    }
    __syncthreads();

    // ---- acc2 = S @ v; epilogue ----
    float acc2[4][4] = {};
    for (int c = 0; c < BT; c += 4){
        float zr[4][4], xv[4][4];
        #pragma unroll
        for (int j = 0; j < 4; ++j){
            float4 t4 = *(const float4*)&Z[r0 + j][c];
            zr[j][0] = t4.x; zr[j][1] = t4.y; zr[j][2] = t4.z; zr[j][3] = t4.w;
        }
        #pragma unroll
        for (int cc = 0; cc < 4; ++cc){
            float4 t4 = *(const float4*)&X[c + cc][v0];
            xv[cc][0] = t4.x; xv[cc][1] = t4.y; xv[cc][2] = t4.z; xv[cc][3] = t4.w;
        }
        #pragma unroll
        for (int j = 0; j < 4; ++j)
            #pragma unroll
            for (int jj = 0; jj < 4; ++jj)
                #pragma unroll
                for (int cc = 0; cc < 4; ++cc)
                    acc2[j][jj] = fmaf(zr[j][cc], xv[cc][jj], acc2[j][jj]);
    }
    #pragma unroll
    for (int j = 0; j < 4; ++j){
        int r = r0 + j;
        float rf = rowfac[r];
        float inv = 1.f / denom[r];
        float4 h4;
        h4.x = (acc1[j][0] * rf + acc2[j][0]) * inv;
        h4.y = (acc1[j][1] * rf + acc2[j][1]) * inv;
        h4.z = (acc1[j][2] * rf + acc2[j][2]) * inv;
        h4.w = (acc1[j][3] * rf + acc2[j][3]) * inv;
        *(float4*)(out + (rowbase + r) * DV + v0) = h4;
    }
}

// ============ Mid fallback: old sequential pass1 (slab-major C) ============
__global__ __launch_bounds__(256) void pass1_kernel(
    const float* __restrict__ kg, const float* __restrict__ vg,
    const float* __restrict__ ig, const float* __restrict__ fg,
    float* __restrict__ Cws, float* __restrict__ nws, float* __restrict__ mws,
    int T, int NT)
{
    const int vb  = blockIdx.x;
    const int s   = blockIdx.y;
    const int tid = threadIdx.x;
    const int lane = tid & 63;

    __shared__ float kbuf[BT][DK];
    __shared__ float vbuf[BT][16];
    __shared__ float gscale[BT];
    __shared__ float sh_dec;

    const float* kseq = kg + (size_t)s * T * DK;
    const float* vseq = vg + (size_t)s * T * DV + vb * 16;
    const float* iseq = ig + (size_t)s * T;
    const float* fseq = fg + (size_t)s * T;

    const int kk  = tid >> 2;
    const int vv0 = (tid & 3) * 4;

    float Creg[4] = {0.f, 0.f, 0.f, 0.f};
    float nreg = 0.f;
    float m = 0.f;

    for (int t = 0; t < NT; ++t){
        {
            size_t off = (((size_t)(s * NT + t)) * 4 + vb) * 1024 + kk * 16 + vv0;
            *(float4*)(Cws + off) = make_float4(Creg[0], Creg[1], Creg[2], Creg[3]);
            if (vb == 0 && tid < 64) nws[((size_t)(s * NT + t)) * DK + lane] = nreg;
            if (vb == 0 && tid == 0) mws[s * NT + t] = m;
        }
        if (tid < 64){
            float b = logsig_log2e(fseq[t * BT + lane]);
            #pragma unroll
            for (int off = 1; off < 64; off <<= 1){
                float y = __shfl_up(b, off);
                if (lane >= off) b += y;
            }
            float f_last = __shfl(b, 63);
            float g = iseq[t * BT + lane] * LOG2E_F + f_last - b;
            float gm = g;
            #pragma unroll
            for (int off = 32; off > 0; off >>= 1) gm = fmaxf(gm, __shfl_xor(gm, off));
            float m_next = fmaxf(f_last + m, gm);
            gscale[lane] = exp2f(g - m_next);
            if (tid == 0) sh_dec = exp2f(f_last + m - m_next);
            m = m_next;
        }
        {
            const float* kc = kseq + (size_t)t * BT * DK;
            #pragma unroll
            for (int base = 0; base < BT * DK; base += 1024){
                int idx = base + tid * 4;
                float4 t4 = *(const float4*)(kc + idx);
                int r = idx >> 6, c = idx & 63;
                kbuf[r][c] = t4.x; kbuf[r][c+1] = t4.y; kbuf[r][c+2] = t4.z; kbuf[r][c+3] = t4.w;
            }
            const float* vc = vseq + (size_t)t * BT * DV;
            int idx = tid * 4;
            int r = idx >> 4, j = idx & 15;
            float4 t4 = *(const float4*)(vc + (size_t)r * DV + j);
            vbuf[r][j] = t4.x; vbuf[r][j+1] = t4.y; vbuf[r][j+2] = t4.z; vbuf[r][j+3] = t4.w;
        }
        __syncthreads();
        {
            float dec = sh_dec;
            #pragma unroll
            for (int j = 0; j < 4; ++j) Creg[j] *= dec;
            for (int c = 0; c < BT; ++c){
                float kd = kbuf[c][kk] * gscale[c];
                #pragma unroll
                for (int j = 0; j < 4; ++j)
                    Creg[j] = fmaf(kd, vbuf[c][vv0 + j], Creg[j]);
            }
            if (vb == 0 && tid < 64){
                float acc = 0.f;
                for (int c = 0; c < BT; ++c) acc = fmaf(kbuf[c][lane], gscale[c], acc);
                nreg = nreg * dec + acc;
            }
        }
        __syncthreads();
    }
}

// ---------------- Fallback: fused sequential (no workspace) ----------------
__global__ __launch_bounds__(256) void fused_kernel(
    const float* __restrict__ qg, const float* __restrict__ kg, const float* __restrict__ vg,
    const float* __restrict__ ig, const float* __restrict__ fg,
    float* __restrict__ out, int T, int NT)
{
    const int s = blockIdx.x;
    const int tid = threadIdx.x;
    const int lane = tid & 63;

    __shared__ float X[BT][DK + 1];
    __shared__ float Y[BT][DK + 1];
    __shared__ float Cb[DK][DV];
    __shared__ __hip_bfloat16 Zh[BT][BT];
    __shared__ float colterm[BT], Mr[BT], rowfac[BT], dncl[BT], gscale[BT];
    __shared__ float nsh[DK], qn[BT], rowsum[BT], denom[BT];
    __shared__ float sh_dec;

    const float* qseq = qg + (size_t)s * T * DK;
    const float* kseq = kg + (size_t)s * T * DK;
    const float* vseq = vg + (size_t)s * T * DV;
    const float* iseq = ig + (size_t)s * T;
    const float* fseq = fg + (size_t)s * T;

    for (int idx = tid; idx < DK * DV; idx += 256) Cb[idx >> 6][idx & 63] = 0.f;
    if (tid < 64) nsh[lane] = 0.f;
    float m = 0.f;
    __syncthreads();

    const int r0 = (tid >> 4) * 4;
    const int c0 = (tid & 15) * 4;
    const int v0 = c0;

    for (int t = 0; t < NT; ++t){
        const size_t rb = (size_t)t * BT;
        if (tid < 64){
            float b = logsig_log2e(fseq[rb + lane]);
            #pragma unroll
            for (int off = 1; off < 64; off <<= 1){
                float y = __shfl_up(b, off);
                if (lane >= off) b += y;
            }
            float f_last = __shfl(b, 63);
            float a = iseq[rb + lane] * LOG2E_F - b;
            float p = a;
            #pragma unroll
            for (int off = 1; off < 64; off <<= 1){
                float y = __shfl_up(p, off);
                if (lane >= off) p = fmaxf(p, y);
            }
            float M = fmaxf(m, p);
            colterm[lane] = a;
            Mr[lane] = M;
            rowfac[lane] = SCALE * exp2f(m - M);
            dncl[lane] = exp2f(-(b + M));
            float g = a + f_last;
            float gm = g;
            #pragma unroll
            for (int off = 32; off > 0; off >>= 1) gm = fmaxf(gm, __shfl_xor(gm, off));
            float m_next = fmaxf(f_last + m, gm);
            gscale[lane] = exp2f(g - m_next);
            if (tid == 0) sh_dec = exp2f(f_last + m - m_next);
            m = m_next;
        }
        #pragma unroll
        for (int base = 0; base < BT * DK; base += 1024){
            int idx = base + tid * 4;
            int r = idx >> 6, c = idx & 63;
            float4 a4 = *(const float4*)(qseq + rb * DK + idx);
            X[r][c] = a4.x; X[r][c+1] = a4.y; X[r][c+2] = a4.z; X[r][c+3] = a4.w;
            float4 b4 = *(const float4*)(kseq + rb * DK + idx);
            Y[r][c] = b4.x; Y[r][c+1] = b4.y; Y[r][c+2] = b4.z; Y[r][c+3] = b4.w;
        }
        __syncthreads();

        float sacc[4][4] = {};
        for (int x = 0; x < DK; ++x){
            float xr[4], yc[4];
            #pragma unroll
            for (int j = 0; j < 4; ++j) xr[j] = X[r0 + j][x];
            #pragma unroll
            for (int j = 0; j < 4; ++j) yc[j] = Y[c0 + j][x];
            #pragma unroll
            for (int j = 0; j < 4; ++j)
                #pragma unroll
                for (int jj = 0; jj < 4; ++jj)
                    sacc[j][jj] = fmaf(xr[j], yc[jj], sacc[j][jj]);
        }
        float rs[4];
        #pragma unroll
        for (int j = 0; j < 4; ++j){
            int r = r0 + j;
            float Mrv = Mr[r];
            float acc = 0.f;
            #pragma unroll
            for (int jj = 0; jj < 4; ++jj){
                int c = c0 + jj;
                float vS = (c <= r) ? sacc[j][jj] * SCALE * exp2f(colterm[c] - Mrv) : 0.f;
                Zh[r][c] = __float2bfloat16(vS);
                acc += vS;
            }
            rs[j] = acc;
        }
        #pragma unroll
        for (int off = 1; off < 16; off <<= 1){
            #pragma unroll
            for (int j = 0; j < 4; ++j) rs[j] += __shfl_xor(rs[j], off);
        }
        if ((tid & 15) == 0){
            #pragma unroll
            for (int j = 0; j < 4; ++j) rowsum[r0 + j] = rs[j];
        }
        float acc1[4][4] = {};
        for (int x = 0; x < DK; ++x){
            float xr[4], yv[4];
            #pragma unroll
            for (int j = 0; j < 4; ++j) xr[j] = X[r0 + j][x];
            #pragma unroll
            for (int j = 0; j < 4; ++j) yv[j] = Cb[x][v0 + j];
            #pragma unroll
            for (int j = 0; j < 4; ++j)
                #pragma unroll
                for (int jj = 0; jj < 4; ++jj)
                    acc1[j][jj] = fmaf(xr[j], yv[jj], acc1[j][jj]);
        }
        if (tid < 64){
            float acc = 0.f;
            for (int x = 0; x < DK; ++x) acc = fmaf(X[lane][x], nsh[x], acc);
            qn[lane] = acc;
        }
        __syncthreads();

        #pragma unroll
        for (int base = 0; base < BT * DV; base += 1024){
            int idx = base + tid * 4;
            int r = idx >> 6, c = idx & 63;
            float4 a4 = *(const float4*)(vseq + rb * DV + idx);
            X[r][c] = a4.x; X[r][c+1] = a4.y; X[r][c+2] = a4.z; X[r][c+3] = a4.w;
        }
        if (tid < 64){
            float dn = fabsf(rowfac[lane] * qn[lane] + rowsum[lane]);
            denom[lane] = fmaxf(dn, dncl[lane]);
        }
        __syncthreads();

        float acc2[4][4] = {};
        for (int c = 0; c < BT; ++c){
            float zr[4], xv[4];
            #pragma unroll
            for (int j = 0; j < 4; ++j) zr[j] = __bfloat162float(Zh[r0 + j][c]);
            #pragma unroll
            for (int j = 0; j < 4; ++j) xv[j] = X[c][v0 + j];
            #pragma unroll
            for (int j = 0; j < 4; ++j)
                #pragma unroll
                for (int jj = 0; jj < 4; ++jj)
                    acc2[j][jj] = fmaf(zr[j], xv[jj], acc2[j][jj]);
        }
        #pragma unroll
        for (int j = 0; j < 4; ++j){
            int r = r0 + j;
            float rf = rowfac[r];
            float inv = 1.f / denom[r];
            float4 h4;
            h4.x = (acc1[j][0] * rf + acc2[j][0]) * inv;
            h4.y = (acc1[j][1] * rf + acc2[j][1]) * inv;
            h4.z = (acc1[j][2] * rf + acc2[j][2]) * inv;
            h4.w = (acc1[j][3] * rf + acc2[j][3]) * inv;
            *(float4*)(out + ((size_t)s * T + rb + r) * DV + v0) = h4;
        }
        {
            float dec = sh_dec;
            float cr[4][4];
            #pragma unroll
            for (int j = 0; j < 4; ++j)
                #pragma unroll
                for (int jj = 0; jj < 4; ++jj)
                    cr[j][jj] = Cb[r0 + j][c0 + jj] * dec;
            for (int c = 0; c < BT; ++c){
                float gs = gscale[c];
                float kd[4], xv[4];
                #pragma unroll
                for (int j = 0; j < 4; ++j) kd[j] = Y[c][r0 + j] * gs;
                #pragma unroll
                for (int jj = 0; jj < 4; ++jj) xv[jj] = X[c][c0 + jj];
                #pragma unroll
                for (int j = 0; j < 4; ++j)
                    #pragma unroll
                    for (int jj = 0; jj < 4; ++jj)
                        cr[j][jj] = fmaf(kd[j], xv[jj], cr[j][jj]);
            }
            #pragma unroll
            for (int j = 0; j < 4; ++j)
                #pragma unroll
                for (int jj = 0; jj < 4; ++jj)
                    Cb[r0 + j][c0 + jj] = cr[j][jj];
        }
        if (tid < 64){
            float acc = 0.f;
            for (int c = 0; c < BT; ++c) acc = fmaf(Y[c][lane], gscale[c], acc);
            nsh[lane] = nsh[lane] * sh_dec + acc;
        }
        __syncthreads();
    }
}

extern "C" void kernel_launch(void* const* d_in, const int* in_sizes, int n_in,
                              void* d_out, int out_size, void* d_ws, size_t ws_size,
                              hipStream_t stream)
{
    const float* q  = (const float*)d_in[0];
    const float* k  = (const float*)d_in[1];
    const float* v  = (const float*)d_in[2];
    const float* ii = (const float*)d_in[3];
    const float* ff = (const float*)d_in[4];
    float* out = (float*)d_out;

    const int T  = 4096;
    const int BH = in_sizes[3] / T;
    const int NT = T / BT;

    const size_t szC  = (size_t)BH * NT * DK * DV * sizeof(float);  // 67 MB
    const size_t szA  = szC;
    const size_t szn  = (size_t)BH * NT * DK * sizeof(float);       // 1 MB
    const size_t szs  = (size_t)BH * NT * sizeof(float);            // 16 KB

    const size_t need_new = szA + szC + 2 * szn + 3 * szs;
    const size_t need_old = szC + szn + szs;

    if (ws_size >= need_new){
        char* p = (char*)d_ws;
        float* A_ws    = (float*)p;            p += szA;
        float* Cws     = (float*)p;            p += szC;
        float* nloc_ws = (float*)p;            p += szn;
        float* nws     = (float*)p;            p += szn;
        float* fl_ws   = (float*)p;            p += szs;
        float* mloc_ws = (float*)p;            p += szs;
        float* mws     = (float*)p;
        stageA_kernel<<<dim3(NT, BH), 256, 0, stream>>>(k, v, ii, ff, A_ws, nloc_ws, fl_ws, mloc_ws, T, NT);
        stageB_kernel<<<dim3(4, BH), 256, 0, stream>>>(A_ws, nloc_ws, fl_ws, mloc_ws, Cws, nws, mws, NT);
        pass2_kernel<<<dim3(NT, BH), 256, 0, stream>>>(q, k, v, ii, ff, Cws, nws, mws, out, T, NT);
    } else if (ws_size >= need_old){
        float* Cws = (float*)d_ws;
        float* nws = (float*)((char*)d_ws + szC);
        float* mws = (float*)((char*)d_ws + szC + szn);
        pass1_kernel<<<dim3(4, BH), 256, 0, stream>>>(k, v, ii, ff, Cws, nws, mws, T, NT);
        pass2_kernel<<<dim3(NT, BH), 256, 0, stream>>>(q, k, v, ii, ff, Cws, nws, mws, out, T, NT);
    } else {
        fused_kernel<<<dim3(BH), 256, 0, stream>>>(q, k, v, ii, ff, out, T, NT);
    }
}

// Round 4
// 310.653 us; speedup vs baseline: 4.8888x; 4.8888x over previous
//
#include <hip/hip_runtime.h>
#include <hip/hip_bf16.h>
#include <math.h>

#define LOG2E_F 1.4426950408889634f

static constexpr int BT = 64;
static constexpr int DK = 64;
static constexpr int DV = 64;
static constexpr float SCALE = 0.125f;
static constexpr int PAD = 72;   // ushort row stride: 144 B, 16B-aligned, uniform banks for b128 frags

typedef unsigned short ushort_t;
typedef __attribute__((ext_vector_type(8))) short short8;
typedef __attribute__((ext_vector_type(4))) float f32x4;
typedef __attribute__((ext_vector_type(4))) ushort_t ushort4v;

#define MFMA16(a, b, c) __builtin_amdgcn_mfma_f32_16x16x32_bf16((a), (b), (c), 0, 0, 0)

__device__ __forceinline__ float logsig_log2e(float x){
    float l = (x >= 0.f) ? (-log1pf(expf(-x))) : (x - log1pf(expf(x)));
    return l * LOG2E_F;
}
__device__ __forceinline__ ushort_t f2bf(float x){   // RNE f32 -> bf16 bits
    unsigned u = __builtin_bit_cast(unsigned, x);
    unsigned r = u + 0x7FFFu + ((u >> 16) & 1u);
    return (ushort_t)(r >> 16);
}
__device__ __forceinline__ float bf2f(ushort_t u){
    return __builtin_bit_cast(float, ((unsigned)u) << 16);
}
// split x = hi + lo (hi RNE bf16; residual exact; combined ~17 mantissa bits)
__device__ __forceinline__ void split_bf(float x, ushort_t& h, ushort_t& l){
    h = f2bf(x);
    l = f2bf(x - bf2f(h));
}

// ===================== Stage A: per-chunk local state (split-bf16 MFMA) ==========
// A_t = kdec_loc^T @ v  (kdim x vdim), nloc = colsum(kdec_loc), fl, mloc.
// A stored f32 slab-major: [(s*NT+t)*4 + vslab][krow][16].
__global__ __launch_bounds__(256) void stageA_kernel(
    const float* __restrict__ kg, const float* __restrict__ vg,
    const float* __restrict__ ig, const float* __restrict__ fg,
    float* __restrict__ A_ws, float* __restrict__ nloc_ws,
    float* __restrict__ fl_ws, float* __restrict__ mloc_ws,
    int T, int NT)
{
    const int ct = blockIdx.x, s = blockIdx.y, tid = threadIdx.x;
    const int w = tid >> 6, lane = tid & 63, ln = lane & 15, quad = lane >> 4;
    const int q8 = quad * 8;

    __shared__ __align__(16) ushort_t kth[DK][PAD];  // kdec^T hi  [kdim][row]
    __shared__ __align__(16) ushort_t ktl[DK][PAD];  // kdec^T lo
    __shared__ __align__(16) ushort_t vth[DV][PAD];  // v^T hi     [vdim][row]
    __shared__ __align__(16) ushort_t vtl[DV][PAD];  // v^T lo
    __shared__ float gsc[BT];

    const size_t rowbase = (size_t)s * T + (size_t)ct * BT;
    const float* kc = kg + rowbase * DK;
    const float* vc = vg + rowbase * DV;

    float4 kr[4], vr[4];
    #pragma unroll
    for (int i = 0; i < 4; ++i){
        int idx = i * 1024 + tid * 4;
        kr[i] = *(const float4*)(kc + idx);
        vr[i] = *(const float4*)(vc + idx);
    }
    if (tid < 64){
        float b = logsig_log2e(fg[rowbase + tid]);
        #pragma unroll
        for (int off = 1; off < 64; off <<= 1){
            float y = __shfl_up(b, off);
            if (tid >= off) b += y;
        }
        float f_last = __shfl(b, 63);
        float a = ig[rowbase + tid] * LOG2E_F - b;
        float p = a;
        #pragma unroll
        for (int off = 32; off > 0; off >>= 1) p = fmaxf(p, __shfl_xor(p, off));
        gsc[tid] = exp2f(a - p);
        if (tid == 0){ fl_ws[s * NT + ct] = f_last; mloc_ws[s * NT + ct] = f_last + p; }
    }
    __syncthreads();
    // transpose-stage split-bf16 (k scaled by gsc[row])
    #pragma unroll
    for (int i = 0; i < 4; ++i){
        int idx = i * 1024 + tid * 4;
        int r = idx >> 6, c0 = idx & 63;
        float g = gsc[r];
        float kv[4] = {kr[i].x * g, kr[i].y * g, kr[i].z * g, kr[i].w * g};
        float vv[4] = {vr[i].x, vr[i].y, vr[i].z, vr[i].w};
        #pragma unroll
        for (int j = 0; j < 4; ++j){
            ushort_t h, l;
            split_bf(kv[j], h, l); kth[c0 + j][r] = h; ktl[c0 + j][r] = l;
            split_bf(vv[j], h, l); vth[c0 + j][r] = h; vtl[c0 + j][r] = l;
        }
    }
    __syncthreads();

    const int m = 16 * w + ln;
    short8 ah0 = *(const short8*)&kth[m][q8];
    short8 ah1 = *(const short8*)&kth[m][32 + q8];
    short8 al0 = *(const short8*)&ktl[m][q8];
    short8 al1 = *(const short8*)&ktl[m][32 + q8];
    float* Ab = A_ws + (size_t)(s * NT + ct) * 4096;
    #pragma unroll
    for (int t = 0; t < 4; ++t){
        f32x4 acc = {0.f, 0.f, 0.f, 0.f};
        short8 bh0 = *(const short8*)&vth[16 * t + ln][q8];
        short8 bh1 = *(const short8*)&vth[16 * t + ln][32 + q8];
        short8 bl0 = *(const short8*)&vtl[16 * t + ln][q8];
        short8 bl1 = *(const short8*)&vtl[16 * t + ln][32 + q8];
        acc = MFMA16(ah0, bh0, acc);
        acc = MFMA16(ah1, bh1, acc);
        acc = MFMA16(ah0, bl0, acc);
        acc = MFMA16(ah1, bl1, acc);
        acc = MFMA16(al0, bh0, acc);
        acc = MFMA16(al1, bh1, acc);
        #pragma unroll
        for (int reg = 0; reg < 4; ++reg){
            int row = 16 * w + quad * 4 + reg;
            Ab[t * 1024 + row * 16 + ln] = acc[reg];
        }
    }
    if (tid < 64){
        float a = 0.f;
        #pragma unroll
        for (int c = 0; c < BT; ++c) a += bf2f(kth[tid][c]) + bf2f(ktl[tid][c]);
        nloc_ws[((size_t)(s * NT + ct)) * DK + tid] = a;
    }
}

// ===================== Stage B: sequential combine (fp32) =====================
__global__ __launch_bounds__(256) void stageB_kernel(
    const float* __restrict__ A_ws, const float* __restrict__ nloc_ws,
    const float* __restrict__ fl_ws, const float* __restrict__ mloc_ws,
    float* __restrict__ Cws, float* __restrict__ nws, float* __restrict__ mws,
    int NT)
{
    const int vb = blockIdx.x, s = blockIdx.y, tid = threadIdx.x;
    __shared__ float decs[64], scs[64];

    if (tid < 64){
        float fl = fl_ws[s * NT + tid];
        float ml = mloc_ws[s * NT + tid];
        float F = fl, G = ml;
        #pragma unroll
        for (int off = 1; off < 64; off <<= 1){
            float Fp = __shfl_up(F, off);
            float Gp = __shfl_up(G, off);
            if (tid >= off){ G = fmaxf(Gp + F, G); F = Fp + F; }
        }
        float m_next = fmaxf(F, G);
        float m_cur  = __shfl_up(m_next, 1);
        if (tid == 0) m_cur = 0.f;
        decs[tid] = exp2f(fl + m_cur - m_next);
        scs[tid]  = exp2f(ml - m_next);
        if (vb == 0) mws[s * NT + tid] = m_cur;
    }
    __syncthreads();

    const size_t base = (size_t)s * NT * 4096 + (size_t)vb * 1024 + tid * 4;
    const float* Ab = A_ws + base;
    float*       Cb = Cws  + base;
    const bool do_n = (vb == 0) && (tid < 64);

    float4 C4 = make_float4(0.f, 0.f, 0.f, 0.f);
    float nreg = 0.f;
    float4 p[8]; float nl[8];
    #pragma unroll
    for (int i = 0; i < 8; ++i){
        p[i] = *(const float4*)(Ab + (size_t)i * 4096);
        nl[i] = 0.f;
    }
    if (do_n){
        #pragma unroll
        for (int i = 0; i < 8; ++i) nl[i] = nloc_ws[((size_t)(s * NT + i)) * DK + tid];
    }
    const float4 z4 = make_float4(0.f, 0.f, 0.f, 0.f);

    for (int t0 = 0; t0 < NT; t0 += 8){
        float4 q[8]; float nq[8];
        const int tn = t0 + 8;
        #pragma unroll
        for (int i = 0; i < 8; ++i)
            q[i] = (tn + i < NT) ? *(const float4*)(Ab + (size_t)(tn + i) * 4096) : z4;
        #pragma unroll
        for (int i = 0; i < 8; ++i) nq[i] = 0.f;
        if (do_n){
            #pragma unroll
            for (int i = 0; i < 8; ++i)
                if (tn + i < NT) nq[i] = nloc_ws[((size_t)(s * NT + tn + i)) * DK + tid];
        }
        #pragma unroll
        for (int i = 0; i < 8; ++i){
            const int t = t0 + i;
            *(float4*)(Cb + (size_t)t * 4096) = C4;
            if (do_n) nws[((size_t)(s * NT + t)) * DK + tid] = nreg;
            const float d = decs[t], sc = scs[t];
            C4.x = C4.x * d + p[i].x * sc;
            C4.y = C4.y * d + p[i].y * sc;
            C4.z = C4.z * d + p[i].z * sc;
            C4.w = C4.w * d + p[i].w * sc;
            if (do_n) nreg = nreg * d + nl[i] * sc;
        }
        #pragma unroll
        for (int i = 0; i < 8; ++i){ p[i] = q[i]; nl[i] = nq[i]; }
    }
}

// ===================== Pass 2: per-chunk outputs (split-bf16 MFMA) ==============
__global__ __launch_bounds__(256) void pass2_kernel(
    const float* __restrict__ qg, const float* __restrict__ kg, const float* __restrict__ vg,
    const float* __restrict__ ig, const float* __restrict__ fg,
    const float* __restrict__ Cws, const float* __restrict__ nws, const float* __restrict__ mws,
    float* __restrict__ out, int T, int NT)
{
    const int ct = blockIdx.x, s = blockIdx.y, tid = threadIdx.x;
    const int w = tid >> 6, lane = tid & 63, ln = lane & 15, quad = lane >> 4;
    const int q8 = quad * 8;

    __shared__ __align__(16) ushort_t q_hi[BT][PAD];   // natural [row][k]
    __shared__ __align__(16) ushort_t q_lo[BT][PAD];
    __shared__ __align__(16) ushort_t kC_hi[BT][PAD];  // k natural -> C^T [v][k]
    __shared__ __align__(16) ushort_t kC_lo[BT][PAD];
    __shared__ __align__(16) ushort_t vt_hi[DV][PAD];  // v^T [vdim][row] (hi only)
    __shared__ __align__(16) ushort_t Z_bf[BT][PAD];   // S [row][col] (single bf16)
    __shared__ float colterm[BT], Mr[BT], rowfac[BT], dncl[BT];
    __shared__ float nsh[DK], qn[BT], rowsum[BT];

    const size_t rowbase = (size_t)s * T + (size_t)ct * BT;
    const float* qc = qg + rowbase * DK;
    const float* kc = kg + rowbase * DK;
    const float* vc = vg + rowbase * DV;
    const float* Cc = Cws + ((size_t)(s * NT + ct)) * 4096;   // slab-major
    const float* nc = nws + ((size_t)(s * NT + ct)) * DK;
    const float m   = mws[s * NT + ct];

    // global loads in flight
    float4 qr[4], kr4[4], vr[4], Cr[4];
    #pragma unroll
    for (int i = 0; i < 4; ++i){
        int idx = i * 1024 + tid * 4;
        qr[i]  = *(const float4*)(qc + idx);
        kr4[i] = *(const float4*)(kc + idx);
        vr[i]  = *(const float4*)(vc + idx);
        Cr[i]  = *(const float4*)(Cc + idx);
    }
    // gates
    if (tid < 64){
        float b = logsig_log2e(fg[rowbase + tid]);
        #pragma unroll
        for (int off = 1; off < 64; off <<= 1){
            float y = __shfl_up(b, off);
            if (tid >= off) b += y;
        }
        float a = ig[rowbase + tid] * LOG2E_F - b;
        float p = a;
        #pragma unroll
        for (int off = 1; off < 64; off <<= 1){
            float y = __shfl_up(p, off);
            if (tid >= off) p = fmaxf(p, y);
        }
        float M = fmaxf(m, p);
        colterm[tid] = a;
        Mr[tid] = M;
        rowfac[tid] = SCALE * exp2f(m - M);
        dncl[tid] = exp2f(-(b + M));
        nsh[tid] = nc[tid];
    }
    // stage q,k (natural, split) and v^T (hi only)
    #pragma unroll
    for (int i = 0; i < 4; ++i){
        int idx = i * 1024 + tid * 4;
        int r = idx >> 6, c0 = idx & 63;
        float qv[4] = {qr[i].x, qr[i].y, qr[i].z, qr[i].w};
        float kv[4] = {kr4[i].x, kr4[i].y, kr4[i].z, kr4[i].w};
        float vv[4] = {vr[i].x, vr[i].y, vr[i].z, vr[i].w};
        ushort4v qh4, ql4, kh4, kl4;
        #pragma unroll
        for (int j = 0; j < 4; ++j){
            ushort_t h, l;
            split_bf(qv[j], h, l); qh4[j] = h; ql4[j] = l;
            split_bf(kv[j], h, l); kh4[j] = h; kl4[j] = l;
            vt_hi[c0 + j][r] = f2bf(vv[j]);
        }
        *(ushort4v*)&q_hi[r][c0] = qh4;
        *(ushort4v*)&q_lo[r][c0] = ql4;
        *(ushort4v*)&kC_hi[r][c0] = kh4;
        *(ushort4v*)&kC_lo[r][c0] = kl4;
    }
    __syncthreads();

    const int mrow = 16 * w + ln;
    short8 ah0 = *(const short8*)&q_hi[mrow][q8];
    short8 ah1 = *(const short8*)&q_hi[mrow][32 + q8];
    short8 al0 = *(const short8*)&q_lo[mrow][q8];
    short8 al1 = *(const short8*)&q_lo[mrow][32 + q8];

    // qn[mrow] = sum_k q*n   (fp32, from recombined fragments)
    {
        float p = 0.f;
        #pragma unroll
        for (int j = 0; j < 8; ++j){
            float qv0 = bf2f((ushort_t)ah0[j]) + bf2f((ushort_t)al0[j]);
            float qv1 = bf2f((ushort_t)ah1[j]) + bf2f((ushort_t)al1[j]);
            p = fmaf(qv0, nsh[q8 + j], p);
            p = fmaf(qv1, nsh[32 + q8 + j], p);
        }
        p += __shfl_xor(p, 16);
        p += __shfl_xor(p, 32);
        if (quad == 0) qn[mrow] = p;
    }

    // ---- S = q @ k^T (3-product split) ----
    f32x4 sacc[4];
    #pragma unroll
    for (int t = 0; t < 4; ++t){
        sacc[t] = (f32x4){0.f, 0.f, 0.f, 0.f};
        short8 bh0 = *(const short8*)&kC_hi[16 * t + ln][q8];
        short8 bh1 = *(const short8*)&kC_hi[16 * t + ln][32 + q8];
        short8 bl0 = *(const short8*)&kC_lo[16 * t + ln][q8];
        short8 bl1 = *(const short8*)&kC_lo[16 * t + ln][32 + q8];
        sacc[t] = MFMA16(ah0, bh0, sacc[t]);
        sacc[t] = MFMA16(ah1, bh1, sacc[t]);
        sacc[t] = MFMA16(ah0, bl0, sacc[t]);
        sacc[t] = MFMA16(ah1, bl1, sacc[t]);
        sacc[t] = MFMA16(al0, bh0, sacc[t]);
        sacc[t] = MFMA16(al1, bh1, sacc[t]);
    }
    // scale + mask + rowsum (fp32-exact) + write Z
    {
        float rsum[4] = {0.f, 0.f, 0.f, 0.f};
        float Mrv[4];
        #pragma unroll
        for (int reg = 0; reg < 4; ++reg) Mrv[reg] = Mr[16 * w + quad * 4 + reg];
        #pragma unroll
        for (int t = 0; t < 4; ++t){
            int c = 16 * t + ln;
            float cterm = colterm[c];
            #pragma unroll
            for (int reg = 0; reg < 4; ++reg){
                int r = 16 * w + quad * 4 + reg;
                float vS = (c <= r) ? sacc[t][reg] * SCALE * exp2f(cterm - Mrv[reg]) : 0.f;
                Z_bf[r][c] = f2bf(vS);
                rsum[reg] += vS;
            }
        }
        #pragma unroll
        for (int off = 1; off < 16; off <<= 1){
            #pragma unroll
            for (int reg = 0; reg < 4; ++reg) rsum[reg] += __shfl_xor(rsum[reg], off);
        }
        if (ln == 0){
            #pragma unroll
            for (int reg = 0; reg < 4; ++reg) rowsum[16 * w + quad * 4 + reg] = rsum[reg];
        }
    }
    __syncthreads();    // all k reads + Z writes complete

    // stage C^T (split) into the dead k tiles
    #pragma unroll
    for (int i = 0; i < 4; ++i){
        int idx = i * 1024 + tid * 4;
        int vsl = idx >> 10, krow = (idx >> 4) & 63, ci = idx & 15;
        int v0 = vsl * 16 + ci;
        float cv[4] = {Cr[i].x, Cr[i].y, Cr[i].z, Cr[i].w};
        #pragma unroll
        for (int j = 0; j < 4; ++j){
            ushort_t h, l;
            split_bf(cv[j], h, l);
            kC_hi[v0 + j][krow] = h;
            kC_lo[v0 + j][krow] = l;
        }
    }
    __syncthreads();

    // ---- acc = (q @ C) * rowfac ----
    f32x4 acc[4];
    #pragma unroll
    for (int t = 0; t < 4; ++t){
        acc[t] = (f32x4){0.f, 0.f, 0.f, 0.f};
        short8 bh0 = *(const short8*)&kC_hi[16 * t + ln][q8];
        short8 bh1 = *(const short8*)&kC_hi[16 * t + ln][32 + q8];
        short8 bl0 = *(const short8*)&kC_lo[16 * t + ln][q8];
        short8 bl1 = *(const short8*)&kC_lo[16 * t + ln][32 + q8];
        acc[t] = MFMA16(ah0, bh0, acc[t]);
        acc[t] = MFMA16(ah1, bh1, acc[t]);
        acc[t] = MFMA16(ah0, bl0, acc[t]);
        acc[t] = MFMA16(ah1, bl1, acc[t]);
        acc[t] = MFMA16(al0, bh0, acc[t]);
        acc[t] = MFMA16(al1, bh1, acc[t]);
    }
    float rf[4], inv[4];
    #pragma unroll
    for (int reg = 0; reg < 4; ++reg){
        int r = 16 * w + quad * 4 + reg;
        rf[reg] = rowfac[r];
        float dn = fabsf(rf[reg] * qn[r] + rowsum[r]);
        inv[reg] = 1.f / fmaxf(dn, dncl[r]);
    }
    #pragma unroll
    for (int t = 0; t < 4; ++t){
        #pragma unroll
        for (int reg = 0; reg < 4; ++reg) acc[t][reg] *= rf[reg];
    }
    // ---- += S @ v ----
    short8 az0 = *(const short8*)&Z_bf[mrow][q8];
    short8 az1 = *(const short8*)&Z_bf[mrow][32 + q8];
    #pragma unroll
    for (int t = 0; t < 4; ++t){
        short8 bh0 = *(const short8*)&vt_hi[16 * t + ln][q8];
        short8 bh1 = *(const short8*)&vt_hi[16 * t + ln][32 + q8];
        acc[t] = MFMA16(az0, bh0, acc[t]);
        acc[t] = MFMA16(az1, bh1, acc[t]);
    }
    // epilogue
    #pragma unroll
    for (int t = 0; t < 4; ++t){
        int c = 16 * t + ln;
        #pragma unroll
        for (int reg = 0; reg < 4; ++reg){
            int r = 16 * w + quad * 4 + reg;
            out[(rowbase + r) * DV + c] = acc[t][reg] * inv[reg];
        }
    }
}

// ---------------- Fallback: fused sequential fp32 (no workspace) ----------------
__global__ __launch_bounds__(256) void fused_kernel(
    const float* __restrict__ qg, const float* __restrict__ kg, const float* __restrict__ vg,
    const float* __restrict__ ig, const float* __restrict__ fg,
    float* __restrict__ out, int T, int NT)
{
    const int s = blockIdx.x;
    const int tid = threadIdx.x;
    const int lane = tid & 63;

    __shared__ float X[BT][DK + 1];
    __shared__ float Y[BT][DK + 1];
    __shared__ float Cb[DK][DV];
    __shared__ __hip_bfloat16 Zh[BT][BT];
    __shared__ float colterm[BT], Mr[BT], rowfac[BT], dncl[BT], gscale[BT];
    __shared__ float nsh[DK], qn[BT], rowsum[BT], denom[BT];
    __shared__ float sh_dec;

    const float* qseq = qg + (size_t)s * T * DK;
    const float* kseq = kg + (size_t)s * T * DK;
    const float* vseq = vg + (size_t)s * T * DV;
    const float* iseq = ig + (size_t)s * T;
    const float* fseq = fg + (size_t)s * T;

    for (int idx = tid; idx < DK * DV; idx += 256) Cb[idx >> 6][idx & 63] = 0.f;
    if (tid < 64) nsh[lane] = 0.f;
    float m = 0.f;
    __syncthreads();

    const int r0 = (tid >> 4) * 4;
    const int c0 = (tid & 15) * 4;
    const int v0 = c0;

    for (int t = 0; t < NT; ++t){
        const size_t rb = (size_t)t * BT;
        if (tid < 64){
            float b = logsig_log2e(fseq[rb + lane]);
            #pragma unroll
            for (int off = 1; off < 64; off <<= 1){
                float y = __shfl_up(b, off);
                if (lane >= off) b += y;
            }
            float f_last = __shfl(b, 63);
            float a = iseq[rb + lane] * LOG2E_F - b;
            float p = a;
            #pragma unroll
            for (int off = 1; off < 64; off <<= 1){
                float y = __shfl_up(p, off);
                if (lane >= off) p = fmaxf(p, y);
            }
            float M = fmaxf(m, p);
            colterm[lane] = a;
            Mr[lane] = M;
            rowfac[lane] = SCALE * exp2f(m - M);
            dncl[lane] = exp2f(-(b + M));
            float g = a + f_last;
            float gm = g;
            #pragma unroll
            for (int off = 32; off > 0; off >>= 1) gm = fmaxf(gm, __shfl_xor(gm, off));
            float m_next = fmaxf(f_last + m, gm);
            gscale[lane] = exp2f(g - m_next);
            if (tid == 0) sh_dec = exp2f(f_last + m - m_next);
            m = m_next;
        }
        #pragma unroll
        for (int base = 0; base < BT * DK; base += 1024){
            int idx = base + tid * 4;
            int r = idx >> 6, c = idx & 63;
            float4 a4 = *(const float4*)(qseq + rb * DK + idx);
            X[r][c] = a4.x; X[r][c+1] = a4.y; X[r][c+2] = a4.z; X[r][c+3] = a4.w;
            float4 b4 = *(const float4*)(kseq + rb * DK + idx);
            Y[r][c] = b4.x; Y[r][c+1] = b4.y; Y[r][c+2] = b4.z; Y[r][c+3] = b4.w;
        }
        __syncthreads();

        float sacc[4][4] = {};
        for (int x = 0; x < DK; ++x){
            float xr[4], yc[4];
            #pragma unroll
            for (int j = 0; j < 4; ++j) xr[j] = X[r0 + j][x];
            #pragma unroll
            for (int j = 0; j < 4; ++j) yc[j] = Y[c0 + j][x];
            #pragma unroll
            for (int j = 0; j < 4; ++j)
                #pragma unroll
                for (int jj = 0; jj < 4; ++jj)
                    sacc[j][jj] = fmaf(xr[j], yc[jj], sacc[j][jj]);
        }
        float rs[4];
        #pragma unroll
        for (int j = 0; j < 4; ++j){
            int r = r0 + j;
            float Mrv = Mr[r];
            float acc = 0.f;
            #pragma unroll
            for (int jj = 0; jj < 4; ++jj){
                int c = c0 + jj;
                float vS = (c <= r) ? sacc[j][jj] * SCALE * exp2f(colterm[c] - Mrv) : 0.f;
                Zh[r][c] = __float2bfloat16(vS);
                acc += vS;
            }
            rs[j] = acc;
        }
        #pragma unroll
        for (int off = 1; off < 16; off <<= 1){
            #pragma unroll
            for (int j = 0; j < 4; ++j) rs[j] += __shfl_xor(rs[j], off);
        }
        if ((tid & 15) == 0){
            #pragma unroll
            for (int j = 0; j < 4; ++j) rowsum[r0 + j] = rs[j];
        }
        float acc1[4][4] = {};
        for (int x = 0; x < DK; ++x){
            float xr[4], yv[4];
            #pragma unroll
            for (int j = 0; j < 4; ++j) xr[j] = X[r0 + j][x];
            #pragma unroll
            for (int j = 0; j < 4; ++j) yv[j] = Cb[x][v0 + j];
            #pragma unroll
            for (int j = 0; j < 4; ++j)
                #pragma unroll
                for (int jj = 0; jj < 4; ++jj)
                    acc1[j][jj] = fmaf(xr[j], yv[jj], acc1[j][jj]);
        }
        if (tid < 64){
            float acc = 0.f;
            for (int x = 0; x < DK; ++x) acc = fmaf(X[lane][x], nsh[x], acc);
            qn[lane] = acc;
        }
        __syncthreads();

        #pragma unroll
        for (int base = 0; base < BT * DV; base += 1024){
            int idx = base + tid * 4;
            int r = idx >> 6, c = idx & 63;
            float4 a4 = *(const float4*)(vseq + rb * DV + idx);
            X[r][c] = a4.x; X[r][c+1] = a4.y; X[r][c+2] = a4.z; X[r][c+3] = a4.w;
        }
        if (tid < 64){
            float dn = fabsf(rowfac[lane] * qn[lane] + rowsum[lane]);
            denom[lane] = fmaxf(dn, dncl[lane]);
        }
        __syncthreads();

        float acc2[4][4] = {};
        for (int c = 0; c < BT; ++c){
            float zr[4], xv[4];
            #pragma unroll
            for (int j = 0; j < 4; ++j) zr[j] = __bfloat162float(Zh[r0 + j][c]);
            #pragma unroll
            for (int j = 0; j < 4; ++j) xv[j] = X[c][v0 + j];
            #pragma unroll
            for (int j = 0; j < 4; ++j)
                #pragma unroll
                for (int jj = 0; jj < 4; ++jj)
                    acc2[j][jj] = fmaf(zr[j], xv[jj], acc2[j][jj]);
        }
        #pragma unroll
        for (int j = 0; j < 4; ++j){
            int r = r0 + j;
            float rf = rowfac[r];
            float inv = 1.f / denom[r];
            float4 h4;
            h4.x = (acc1[j][0] * rf + acc2[j][0]) * inv;
            h4.y = (acc1[j][1] * rf + acc2[j][1]) * inv;
            h4.z = (acc1[j][2] * rf + acc2[j][2]) * inv;
            h4.w = (acc1[j][3] * rf + acc2[j][3]) * inv;
            *(float4*)(out + ((size_t)s * T + rb + r) * DV + v0) = h4;
        }
        {
            float dec = sh_dec;
            float cr[4][4];
            #pragma unroll
            for (int j = 0; j < 4; ++j)
                #pragma unroll
                for (int jj = 0; jj < 4; ++jj)
                    cr[j][jj] = Cb[r0 + j][c0 + jj] * dec;
            for (int c = 0; c < BT; ++c){
                float gs = gscale[c];
                float kd[4], xv[4];
                #pragma unroll
                for (int j = 0; j < 4; ++j) kd[j] = Y[c][r0 + j] * gs;
                #pragma unroll
                for (int jj = 0; jj < 4; ++jj) xv[jj] = X[c][c0 + jj];
                #pragma unroll
                for (int j = 0; j < 4; ++j)
                    #pragma unroll
                    for (int jj = 0; jj < 4; ++jj)
                        cr[j][jj] = fmaf(kd[j], xv[jj], cr[j][jj]);
            }
            #pragma unroll
            for (int j = 0; j < 4; ++j)
                #pragma unroll
                for (int jj = 0; jj < 4; ++jj)
                    Cb[r0 + j][c0 + jj] = cr[j][jj];
        }
        if (tid < 64){
            float acc = 0.f;
            for (int c = 0; c < BT; ++c) acc = fmaf(Y[c][lane], gscale[c], acc);
            nsh[lane] = nsh[lane] * sh_dec + acc;
        }
        __syncthreads();
    }
}

extern "C" void kernel_launch(void* const* d_in, const int* in_sizes, int n_in,
                              void* d_out, int out_size, void* d_ws, size_t ws_size,
                              hipStream_t stream)
{
    const float* q  = (const float*)d_in[0];
    const float* k  = (const float*)d_in[1];
    const float* v  = (const float*)d_in[2];
    const float* ii = (const float*)d_in[3];
    const float* ff = (const float*)d_in[4];
    float* out = (float*)d_out;

    const int T  = 4096;
    const int BH = in_sizes[3] / T;
    const int NT = T / BT;

    const size_t szC  = (size_t)BH * NT * DK * DV * sizeof(float);
    const size_t szA  = szC;
    const size_t szn  = (size_t)BH * NT * DK * sizeof(float);
    const size_t szs  = (size_t)BH * NT * sizeof(float);

    const size_t need_new = szA + szC + 2 * szn + 3 * szs;

    if (ws_size >= need_new){
        char* p = (char*)d_ws;
        float* A_ws    = (float*)p;            p += szA;
        float* Cws     = (float*)p;            p += szC;
        float* nloc_ws = (float*)p;            p += szn;
        float* nws     = (float*)p;            p += szn;
        float* fl_ws   = (float*)p;            p += szs;
        float* mloc_ws = (float*)p;            p += szs;
        float* mws     = (float*)p;
        stageA_kernel<<<dim3(NT, BH), 256, 0, stream>>>(k, v, ii, ff, A_ws, nloc_ws, fl_ws, mloc_ws, T, NT);
        stageB_kernel<<<dim3(4, BH), 256, 0, stream>>>(A_ws, nloc_ws, fl_ws, mloc_ws, Cws, nws, mws, NT);
        pass2_kernel<<<dim3(NT, BH), 256, 0, stream>>>(q, k, v, ii, ff, Cws, nws, mws, out, T, NT);
    } else {
        fused_kernel<<<dim3(BH), 256, 0, stream>>>(q, k, v, ii, ff, out, T, NT);
    }
}